// Round 8
// baseline (259.320 us; speedup 1.0000x reference)
//
#include <hip/hip_runtime.h>
#include <hip/hip_bf16.h>
#include <math.h>

#define D_MODEL 512
#define N_HEADS 8
#define D_HEAD 64
#define D_FF 2048
#define SEQ 2048
#define BATCH 4
#define NTOK (BATCH * SEQ)
#define QSCALE 0.04419417382415922f          // 1/sqrt(512)
#define QSCALE_L2E (-QSCALE * 1.44269504089f) // fold -log2(e)*scale into Q

typedef unsigned short ushort_t;
typedef __attribute__((ext_vector_type(8))) short short8;
typedef __attribute__((ext_vector_type(4))) float float4v;

static __device__ __forceinline__ ushort_t f2bf(float f) {
    union { float f; unsigned int i; } c; c.f = f;
    unsigned int i = c.i;
    unsigned int r = (i + 0x7FFFu + ((i >> 16) & 1u)) >> 16;   // RNE
    return (ushort_t)r;
}

static __device__ __forceinline__ unsigned int pack2bf(float a, float b) {
    union { __hip_bfloat162 h; unsigned int u; } c;
    c.h = __float22bfloat162_rn(make_float2(a, b));
    return c.u;
}

// sigmoid with scale pre-folded: input st = -s*scale*log2e  ->  1/(1+2^st)
static __device__ __forceinline__ float sig2(float x) {
    return __builtin_amdgcn_rcpf(1.0f + __builtin_amdgcn_exp2f(x));
}

// ------------- weights -> bf16 transposed [N][K], LDS-tiled (coalesced both sides) -------
__global__ __launch_bounds__(256) void k_prep_weights(const float* __restrict__ Wq,
                                                      const float* __restrict__ Wk,
                                                      const float* __restrict__ Wv,
                                                      const float* __restrict__ W1,
                                                      const float* __restrict__ W2,
                                                      ushort_t* __restrict__ Wqkvt,
                                                      ushort_t* __restrict__ W1t,
                                                      ushort_t* __restrict__ W2t) {
    __shared__ ushort_t tile[64][66];
    int bid = blockIdx.x;
    const float* src; ushort_t* dst; int K, N, tk, tn;
    if (bid < 192) {
        int m = bid >> 6, r = bid & 63;
        src = (m == 0) ? Wq : ((m == 1) ? Wk : Wv);
        dst = Wqkvt + (size_t)m * 512 * 512; K = 512; N = 512; tk = r >> 3; tn = r & 7;
    } else if (bid < 448) {
        int r = bid - 192; src = W1; dst = W1t; K = 512; N = 2048; tk = r >> 5; tn = r & 31;
    } else {
        int r = bid - 448; src = W2; dst = W2t; K = 2048; N = 512; tk = r >> 3; tn = r & 7;
    }
    int k0 = tk * 64, n0 = tn * 64;
    int rr = threadIdx.x >> 6, c = threadIdx.x & 63;
#pragma unroll
    for (int i = 0; i < 16; i++) {
        int row = i * 4 + rr;
        tile[row][c] = f2bf(src[(size_t)(k0 + row) * N + n0 + c]);
    }
    __syncthreads();
#pragma unroll
    for (int i = 0; i < 16; i++) {
        int row = i * 4 + rr;   // n-local
        dst[(size_t)(n0 + row) * K + k0 + c] = tile[c][row];
    }
}

// ---------------- layernorm: one wave per 512-wide row, out bf16 ----------------
__global__ __launch_bounds__(256) void k_layernorm(const float* __restrict__ X,
                                                   const float* __restrict__ g,
                                                   const float* __restrict__ be,
                                                   ushort_t* __restrict__ Out) {
    int row  = blockIdx.x * 4 + (threadIdx.x >> 6);
    int lane = threadIdx.x & 63;
    const float* x = X + (size_t)row * D_MODEL + lane * 8;
    float4 v0 = ((const float4*)x)[0];
    float4 v1 = ((const float4*)x)[1];
    float vals[8] = {v0.x, v0.y, v0.z, v0.w, v1.x, v1.y, v1.z, v1.w};
    float s = 0.f, sq = 0.f;
#pragma unroll
    for (int j = 0; j < 8; j++) { s += vals[j]; sq += vals[j] * vals[j]; }
#pragma unroll
    for (int off = 32; off; off >>= 1) { s += __shfl_xor(s, off); sq += __shfl_xor(sq, off); }
    float mu  = s * (1.0f / D_MODEL);
    float var = sq * (1.0f / D_MODEL) - mu * mu;
    float inv = rsqrtf(var + 1e-5f);
    const float* gp  = g  + lane * 8;
    const float* bp  = be + lane * 8;
    float4 g0 = ((const float4*)gp)[0], g1v = ((const float4*)gp)[1];
    float4 b0 = ((const float4*)bp)[0], b1v = ((const float4*)bp)[1];
    float gs[8] = {g0.x, g0.y, g0.z, g0.w, g1v.x, g1v.y, g1v.z, g1v.w};
    float bs[8] = {b0.x, b0.y, b0.z, b0.w, b1v.x, b1v.y, b1v.z, b1v.w};
    ushort_t o[8];
#pragma unroll
    for (int j = 0; j < 8; j++) o[j] = f2bf((vals[j] - mu) * inv * gs[j] + bs[j]);
    ushort_t* op = Out + (size_t)row * D_MODEL + lane * 8;
    *(uint4*)op = *(uint4*)o;
}

// ======== m97-style GEMM core: 128xBN tile, BK=32, global_load_lds double-buffer =========
static __device__ __forceinline__ void stage_tile(const ushort_t* __restrict__ G, int K,
                                                  ushort_t* L, int nchunks, int koff,
                                                  int w, int l) {
#pragma unroll
    for (int n = w; n < nchunks; n += 4) {
        const ushort_t* g = G + (size_t)(n * 16 + (l >> 2)) * K + koff + (l & 3) * 8;
        __builtin_amdgcn_global_load_lds((const __attribute__((address_space(1))) void*)g,
                                         (__attribute__((address_space(3))) void*)(L + n * 512),
                                         16, 0, 0);
    }
}

template <int JW>
static __device__ __forceinline__ void gemm_core2(const ushort_t* __restrict__ A,
                                                  const ushort_t* __restrict__ Bt,
                                                  int K, int m0, int n0,
                                                  ushort_t* As, ushort_t* Bs,
                                                  float4v acc[4][JW]) {
    const int BBUF = JW * 1024;
    int t = threadIdx.x, w = t >> 6, l = t & 63, q = l >> 4, lm = l & 15;
    int mb = (w & 1) * 64, nb = (w >> 1) * (JW * 16);
    const ushort_t* Ab = A + (size_t)m0 * K;
    const ushort_t* Bb = Bt + (size_t)n0 * K;
    int T = K >> 5;

    stage_tile(Ab, K, As, 8, 0, w, l);
    stage_tile(Bb, K, Bs, 2 * JW, 0, w, l);
    __syncthreads();

    for (int kt = 0; kt < T; kt++) {
        int cur = kt & 1;
        if (kt + 1 < T) {
            stage_tile(Ab, K, As + (1 - cur) * 4096, 8, (kt + 1) * 32, w, l);
            stage_tile(Bb, K, Bs + (1 - cur) * BBUF, 2 * JW, (kt + 1) * 32, w, l);
        }
        const ushort_t* asb = As + cur * 4096;
        const ushort_t* bsb = Bs + cur * BBUF;
        short8 a[4], b[JW];
#pragma unroll
        for (int i = 0; i < 4; i++) a[i] = *(const short8*)&asb[(mb + 16 * i + lm) * 32 + q * 8];
#pragma unroll
        for (int j = 0; j < JW; j++) b[j] = *(const short8*)&bsb[(nb + 16 * j + lm) * 32 + q * 8];
#pragma unroll
        for (int i = 0; i < 4; i++)
#pragma unroll
            for (int j = 0; j < JW; j++)
                acc[i][j] = __builtin_amdgcn_mfma_f32_16x16x32_bf16(a[i], b[j], acc[i][j], 0, 0, 0);
        __syncthreads();
    }
}

// ---------------- fused QKV projection (N=1536): q,k head-layout; v transposed ------------
__global__ __launch_bounds__(256) void k_gemm_qkv(const ushort_t* __restrict__ A,
                                                  const ushort_t* __restrict__ Bt,
                                                  const float* __restrict__ bq,
                                                  const float* __restrict__ bk,
                                                  const float* __restrict__ bv,
                                                  ushort_t* __restrict__ qb,
                                                  ushort_t* __restrict__ kb,
                                                  ushort_t* __restrict__ vt) {
    __shared__ __align__(16) ushort_t As[8192];
    __shared__ __align__(16) ushort_t Bs[8192];
    int m0 = blockIdx.x * 128, n0 = blockIdx.y * 128;
    float4v acc[4][4];
#pragma unroll
    for (int i = 0; i < 4; i++)
#pragma unroll
        for (int j = 0; j < 4; j++) acc[i][j] = (float4v){0.f, 0.f, 0.f, 0.f};
    gemm_core2<4>(A, Bt, D_MODEL, m0, n0, As, Bs, acc);

    int t = threadIdx.x, w = t >> 6, l = t & 63, q = l >> 4, lm = l & 15;
    int mb = (w & 1) * 64, nb = (w >> 1) * 64;
    int mat = n0 >> 9, c0 = n0 & 511;
    const float* bias = (mat == 0) ? bq : ((mat == 1) ? bk : bv);
#pragma unroll
    for (int j = 0; j < 4; j++) {
        int cl = c0 + nb + 16 * j + lm;
        int hh = cl >> 6, dh = cl & 63;
        float bvv = bias[cl];
#pragma unroll
        for (int i = 0; i < 4; i++) {
            int mr0 = m0 + mb + 16 * i + q * 4;
            int bb = mr0 >> 11, ss0 = mr0 & (SEQ - 1);
            if (mat == 2) {
                union { ushort_t s[4]; uint2 v; } pk;
#pragma unroll
                for (int r = 0; r < 4; r++) pk.s[r] = f2bf(acc[i][j][r] + bvv);
                *(uint2*)&vt[((size_t)(bb * N_HEADS + hh) * D_HEAD + dh) * SEQ + ss0] = pk.v;
            } else {
                ushort_t* dst = (mat == 0) ? qb : kb;
                float sc = (mat == 0) ? QSCALE_L2E : 1.0f;
#pragma unroll
                for (int r = 0; r < 4; r++)
                    dst[((size_t)(bb * N_HEADS + hh) * SEQ + ss0 + r) * D_HEAD + dh] =
                        f2bf((acc[i][j][r] + bvv) * sc);
            }
        }
    }
}

// ---------------- FFN1: relu(yn @ W1 + b1) -> bf16 row-major ------------------------------
__global__ __launch_bounds__(256) void k_gemm_ffn1(const ushort_t* __restrict__ A,
                                                   const ushort_t* __restrict__ Bt,
                                                   const float* __restrict__ b1,
                                                   ushort_t* __restrict__ hb) {
    __shared__ __align__(16) ushort_t As[8192];
    __shared__ __align__(16) ushort_t Bs[8192];
    int m0 = blockIdx.x * 128, n0 = blockIdx.y * 128;
    float4v acc[4][4];
#pragma unroll
    for (int i = 0; i < 4; i++)
#pragma unroll
        for (int j = 0; j < 4; j++) acc[i][j] = (float4v){0.f, 0.f, 0.f, 0.f};
    gemm_core2<4>(A, Bt, D_MODEL, m0, n0, As, Bs, acc);

    int t = threadIdx.x, w = t >> 6, l = t & 63, q = l >> 4, lm = l & 15;
    int mb = (w & 1) * 64, nb = (w >> 1) * 64;
#pragma unroll
    for (int j = 0; j < 4; j++) {
        int cl = n0 + nb + 16 * j + lm;
        float bvv = b1[cl];
#pragma unroll
        for (int i = 0; i < 4; i++) {
            int mr0 = m0 + mb + 16 * i + q * 4;
#pragma unroll
            for (int r = 0; r < 4; r++)
                hb[(size_t)(mr0 + r) * D_FF + cl] = f2bf(fmaxf(acc[i][j][r] + bvv, 0.f));
        }
    }
}

// ---------------- FFN2: hb @ W2 + b2 + residual -> f32 out (128x64 tile) ------------------
__global__ __launch_bounds__(256) void k_gemm_ffn2(const ushort_t* __restrict__ A,
                                                   const ushort_t* __restrict__ Bt,
                                                   const float* __restrict__ b2,
                                                   const float* __restrict__ res,
                                                   float* __restrict__ out) {
    __shared__ __align__(16) ushort_t As[8192];
    __shared__ __align__(16) ushort_t Bs[4096];
    int m0 = blockIdx.x * 128, n0 = blockIdx.y * 64;
    float4v acc[4][2];
#pragma unroll
    for (int i = 0; i < 4; i++)
#pragma unroll
        for (int j = 0; j < 2; j++) acc[i][j] = (float4v){0.f, 0.f, 0.f, 0.f};
    gemm_core2<2>(A, Bt, D_FF, m0, n0, As, Bs, acc);

    int t = threadIdx.x, w = t >> 6, l = t & 63, q = l >> 4, lm = l & 15;
    int mb = (w & 1) * 64, nb = (w >> 1) * 32;
#pragma unroll
    for (int j = 0; j < 2; j++) {
        int cl = n0 + nb + 16 * j + lm;
        float bvv = b2[cl];
#pragma unroll
        for (int i = 0; i < 4; i++) {
            int mr0 = m0 + mb + 16 * i + q * 4;
#pragma unroll
            for (int r = 0; r < 4; r++) {
                size_t idx = (size_t)(mr0 + r) * D_MODEL + cl;
                out[idx] = acc[i][j][r] + bvv + res[idx];
            }
        }
    }
}

// ---------------- fused sigmoid attention v6: S_w=64 wave-pair t-split --------------------
// 256 thr / 4 waves; block = 128 Q-rows. Wave w: Q-group g=w>>1 (64 rows), t-half th=w&1.
// LDS frag bytes/FLOP = 1/S_w + 1/64: S_w 32->64 cuts per-CU LDS/iter 213->139 KB at equal
// MFMA and per-SIMD sigmoid work. P wave-private (stride-40 rows: 2-way banks only).
__global__ __launch_bounds__(256) void k_attention(const ushort_t* __restrict__ Q,
                                                   const ushort_t* __restrict__ Kb,
                                                   const ushort_t* __restrict__ Vt,
                                                   const float* __restrict__ X,
                                                   float* __restrict__ Y) {
    __shared__ __align__(16) char smem[57344];
    ushort_t* Ks = (ushort_t*)smem;                    // [2][64][72] = 18432 B
    ushort_t* Vs = (ushort_t*)(smem + 18432);          // [2][64][72] = 18432 B (V^T: [d][t])
    ushort_t* Ps = (ushort_t*)(smem + 36864);          // 4 waves x 64 rows x 40 = 20480 B
    float*  Osum = (float*)smem;                       // after loop: 128 x 66 f32 (33.8 KB)

    int bh = blockIdx.y;
    int b = bh >> 3, h = bh & 7;
    size_t base = (size_t)bh * SEQ * D_HEAD;
    int s0 = blockIdx.x * 128;
    int t = threadIdx.x, w = t >> 6, l = t & 63, q = l >> 4, lm = l & 15;
    int g = w >> 1, th = w & 1;
    int srow = t >> 2, sc = (t & 3) * 16;              // staging: 256 thr x 32B = 8 KB tile
    ushort_t* Pw = Ps + w * 2560;                      // wave-private 64x40

    // Q fragments in registers: rows s0 + 64g + 16nt + lm (reused for all 32 K/V tiles)
    short8 qf[4][2];
#pragma unroll
    for (int nt = 0; nt < 4; nt++)
#pragma unroll
        for (int kc = 0; kc < 2; kc++) {
            const ushort_t* qg = Q + base + (size_t)(s0 + 64 * g + 16 * nt + lm) * D_HEAD + kc * 32 + q * 8;
            uint4 u = *(const uint4*)qg;
            qf[nt][kc] = *(const short8*)&u;
        }

    // O partials: o[nt][dj], lane holds O[s=s0+64g+16nt+4q+r][d=16dj+lm]
    float4v o[4][4];
#pragma unroll
    for (int nt = 0; nt < 4; nt++)
#pragma unroll
        for (int dj = 0; dj < 4; dj++) o[nt][dj] = (float4v){0.f, 0.f, 0.f, 0.f};

    uint4 kr0, kr1, vr0, vr1;
    const ushort_t* kg0 = Kb + base + (size_t)srow * D_HEAD + sc;
    const ushort_t* vg0 = Vt + base + (size_t)srow * SEQ + sc;

    kr0 = *(const uint4*)(kg0); kr1 = *(const uint4*)(kg0 + 8);
    vr0 = *(const uint4*)(vg0); vr1 = *(const uint4*)(vg0 + 8);
    *(uint4*)&Ks[srow * 72 + sc] = kr0; *(uint4*)&Ks[srow * 72 + sc + 8] = kr1;
    *(uint4*)&Vs[srow * 72 + sc] = vr0; *(uint4*)&Vs[srow * 72 + sc + 8] = vr1;
    kr0 = *(const uint4*)(kg0 + 64 * D_HEAD); kr1 = *(const uint4*)(kg0 + 64 * D_HEAD + 8);
    vr0 = *(const uint4*)(vg0 + 64);          vr1 = *(const uint4*)(vg0 + 64 + 8);
    __syncthreads();

    for (int tt = 0; tt < SEQ / 64; tt++) {
        int cur = tt & 1;
        const ushort_t* ksb = Ks + cur * 4608;
        const ushort_t* vsb = Vs + cur * 4608;
        // --- K fragments: this wave's t-half (rows 32*th + 16*mt + lm) ---
        short8 kf[2][2];
#pragma unroll
        for (int mt = 0; mt < 2; mt++)
#pragma unroll
            for (int kc = 0; kc < 2; kc++)
                kf[mt][kc] = *(const short8*)&ksb[(32 * th + 16 * mt + lm) * 72 + kc * 32 + q * 8];
        // --- V fragments: rows d=16dj+lm, cols = this wave's t-half (32 t) ---
        short8 vf[4];
#pragma unroll
        for (int dj = 0; dj < 4; dj++)
            vf[dj] = *(const short8*)&vsb[(16 * dj + lm) * 72 + 32 * th + q * 8];
        // --- S^T = K Q~^T : S~[t = tt*64+32th+16mt+4q+r][s = s0+64g+16nt+lm] ---
        float4v st[2][4];
#pragma unroll
        for (int mt = 0; mt < 2; mt++)
#pragma unroll
            for (int nt = 0; nt < 4; nt++) st[mt][nt] = (float4v){0.f, 0.f, 0.f, 0.f};
#pragma unroll
        for (int kc = 0; kc < 2; kc++)
#pragma unroll
            for (int mt = 0; mt < 2; mt++)
#pragma unroll
                for (int nt = 0; nt < 4; nt++)
                    st[mt][nt] = __builtin_amdgcn_mfma_f32_16x16x32_bf16(kf[mt][kc], qf[nt][kc], st[mt][nt], 0, 0, 0);
        // --- sigmoid -> wave-private P (b64; rows s-local 0..63, cols t-half-local 0..31) ---
#pragma unroll
        for (int mt = 0; mt < 2; mt++)
#pragma unroll
            for (int nt = 0; nt < 4; nt++) {
                uint2 pk;
                pk.x = pack2bf(sig2(st[mt][nt][0]), sig2(st[mt][nt][1]));
                pk.y = pack2bf(sig2(st[mt][nt][2]), sig2(st[mt][nt][3]));
                *(uint2*)&Pw[(16 * nt + lm) * 40 + 16 * mt + 4 * q] = pk;
            }
        // --- O += P V over this t-half (K=32, one MFMA k-step per (nt,dj)) ---
#pragma unroll
        for (int nt = 0; nt < 4; nt++) {
            short8 ap = *(const short8*)&Pw[(16 * nt + lm) * 40 + q * 8];
#pragma unroll
            for (int dj = 0; dj < 4; dj++)
                o[nt][dj] = __builtin_amdgcn_mfma_f32_16x16x32_bf16(ap, vf[dj], o[nt][dj], 0, 0, 0);
        }
        // --- pipeline: regs -> other buf; prefetch tt+2 ---
        if (tt + 1 < SEQ / 64) {
            int nxt = 1 - cur;
            *(uint4*)&Ks[nxt * 4608 + srow * 72 + sc] = kr0;
            *(uint4*)&Ks[nxt * 4608 + srow * 72 + sc + 8] = kr1;
            *(uint4*)&Vs[nxt * 4608 + srow * 72 + sc] = vr0;
            *(uint4*)&Vs[nxt * 4608 + srow * 72 + sc + 8] = vr1;
            if (tt + 2 < SEQ / 64) {
                const ushort_t* kg = kg0 + (size_t)(tt + 2) * 64 * D_HEAD;
                const ushort_t* vg = vg0 + (tt + 2) * 64;
                kr0 = *(const uint4*)(kg); kr1 = *(const uint4*)(kg + 8);
                vr0 = *(const uint4*)(vg); vr1 = *(const uint4*)(vg + 8);
            }
        }
        __syncthreads();
    }

    // --- pair-wave O reduction into Osum (smem reused) ---
    __syncthreads();
    if (th == 0) {
#pragma unroll
        for (int nt = 0; nt < 4; nt++)
#pragma unroll
            for (int dj = 0; dj < 4; dj++)
#pragma unroll
                for (int r = 0; r < 4; r++)
                    Osum[(64 * g + 16 * nt + 4 * q + r) * 66 + 16 * dj + lm] = o[nt][dj][r];
    }
    __syncthreads();
    if (th == 1) {
#pragma unroll
        for (int nt = 0; nt < 4; nt++)
#pragma unroll
            for (int dj = 0; dj < 4; dj++)
#pragma unroll
                for (int r = 0; r < 4; r++)
                    Osum[(64 * g + 16 * nt + 4 * q + r) * 66 + 16 * dj + lm] += o[nt][dj][r];
    }
    __syncthreads();

    // --- epilogue: Y = X + O (thread t: row t>>1, 32 cols) ---
    {
        int row = t >> 1, c0 = (t & 1) * 32;
        size_t gro = ((size_t)(b * SEQ + s0 + row)) * D_MODEL + h * D_HEAD + c0;
        const float* xp = X + gro;
        float* yp = Y + gro;
        const float* os = &Osum[row * 66 + c0];
#pragma unroll
        for (int i = 0; i < 8; i++) {
            float4 xv = *(const float4*)(xp + i * 4);
            float4 ov = *(const float4*)(os + i * 4);
            float4 rr;
            rr.x = xv.x + ov.x; rr.y = xv.y + ov.y;
            rr.z = xv.z + ov.z; rr.w = xv.w + ov.w;
            *(float4*)(yp + i * 4) = rr;
        }
    }
}

extern "C" void kernel_launch(void* const* d_in, const int* in_sizes, int n_in,
                              void* d_out, int out_size, void* d_ws, size_t ws_size,
                              hipStream_t stream) {
    const float* x   = (const float*)d_in[0];
    const float* Wq  = (const float*)d_in[1];
    const float* bq  = (const float*)d_in[2];
    const float* Wk  = (const float*)d_in[3];
    const float* bk  = (const float*)d_in[4];
    const float* Wv  = (const float*)d_in[5];
    const float* bv  = (const float*)d_in[6];
    const float* W1  = (const float*)d_in[7];
    const float* b1  = (const float*)d_in[8];
    const float* W2  = (const float*)d_in[9];
    const float* b2  = (const float*)d_in[10];
    const float* g1  = (const float*)d_in[11];
    const float* be1 = (const float*)d_in[12];
    const float* g2  = (const float*)d_in[13];
    const float* be2 = (const float*)d_in[14];
    float* out = (float*)d_out;

    char* p = (char*)d_ws;
    ushort_t* xn    = (ushort_t*)p; p += (size_t)NTOK * D_MODEL * 2;
    ushort_t* yn    = (ushort_t*)p; p += (size_t)NTOK * D_MODEL * 2;
    float*    y     = (float*)p;    p += (size_t)NTOK * D_MODEL * 4;
    ushort_t* qb    = (ushort_t*)p; p += (size_t)NTOK * D_MODEL * 2;
    ushort_t* kb    = (ushort_t*)p; p += (size_t)NTOK * D_MODEL * 2;
    ushort_t* vt    = (ushort_t*)p; p += (size_t)NTOK * D_MODEL * 2;
    ushort_t* hb    = (ushort_t*)p; p += (size_t)NTOK * D_FF * 2;
    ushort_t* Wqkvt = (ushort_t*)p; p += (size_t)3 * D_MODEL * D_MODEL * 2;
    ushort_t* W1t   = (ushort_t*)p; p += (size_t)D_MODEL * D_FF * 2;
    ushort_t* W2t   = (ushort_t*)p; p += (size_t)D_FF * D_MODEL * 2;

    k_prep_weights<<<704, 256, 0, stream>>>(Wq, Wk, Wv, W1, W2, Wqkvt, W1t, W2t);

    k_layernorm<<<NTOK / 4, 256, 0, stream>>>(x, g1, be1, xn);

    dim3 gq(NTOK / 128, (3 * D_MODEL) / 128);
    k_gemm_qkv<<<gq, 256, 0, stream>>>(xn, Wqkvt, bq, bk, bv, qb, kb, vt);

    dim3 ga(SEQ / 128, BATCH * N_HEADS);
    k_attention<<<ga, 256, 0, stream>>>(qb, kb, vt, x, y);

    k_layernorm<<<NTOK / 4, 256, 0, stream>>>(y, g2, be2, yn);

    dim3 g1d(NTOK / 128, D_FF / 128);
    k_gemm_ffn1<<<g1d, 256, 0, stream>>>(yn, W1t, b1, hb);
    dim3 g2d(NTOK / 128, D_MODEL / 64);
    k_gemm_ffn2<<<g2d, 256, 0, stream>>>(hb, W2t, b2, y, out);
}

// Round 9
// 244.961 us; speedup vs baseline: 1.0586x; 1.0586x over previous
//
#include <hip/hip_runtime.h>
#include <hip/hip_bf16.h>
#include <math.h>

#define D_MODEL 512
#define N_HEADS 8
#define D_HEAD 64
#define D_FF 2048
#define SEQ 2048
#define BATCH 4
#define NTOK (BATCH * SEQ)
#define QSCALE 0.04419417382415922f          // 1/sqrt(512)
#define QSCALE_L2E (-QSCALE * 1.44269504089f) // fold -log2(e)*scale into Q

typedef unsigned short ushort_t;
typedef __attribute__((ext_vector_type(8))) short short8;
typedef __attribute__((ext_vector_type(4))) short short4v;
typedef __attribute__((ext_vector_type(4))) float float4v;

static __device__ __forceinline__ ushort_t f2bf(float f) {
    union { float f; unsigned int i; } c; c.f = f;
    unsigned int i = c.i;
    unsigned int r = (i + 0x7FFFu + ((i >> 16) & 1u)) >> 16;   // RNE
    return (ushort_t)r;
}

static __device__ __forceinline__ unsigned int pack2bf(float a, float b) {
    union { __hip_bfloat162 h; unsigned int u; } c;
    c.h = __float22bfloat162_rn(make_float2(a, b));
    return c.u;
}

// sigmoid with scale pre-folded: input st = -s*scale*log2e  ->  1/(1+2^st)
static __device__ __forceinline__ float sig2(float x) {
    return __builtin_amdgcn_rcpf(1.0f + __builtin_amdgcn_exp2f(x));
}

// ------------- weights -> bf16 transposed [N][K], LDS-tiled (coalesced both sides) -------
__global__ __launch_bounds__(256) void k_prep_weights(const float* __restrict__ Wq,
                                                      const float* __restrict__ Wk,
                                                      const float* __restrict__ Wv,
                                                      const float* __restrict__ W1,
                                                      const float* __restrict__ W2,
                                                      ushort_t* __restrict__ Wqkvt,
                                                      ushort_t* __restrict__ W1t,
                                                      ushort_t* __restrict__ W2t) {
    __shared__ ushort_t tile[64][66];
    int bid = blockIdx.x;
    const float* src; ushort_t* dst; int K, N, tk, tn;
    if (bid < 192) {
        int m = bid >> 6, r = bid & 63;
        src = (m == 0) ? Wq : ((m == 1) ? Wk : Wv);
        dst = Wqkvt + (size_t)m * 512 * 512; K = 512; N = 512; tk = r >> 3; tn = r & 7;
    } else if (bid < 448) {
        int r = bid - 192; src = W1; dst = W1t; K = 512; N = 2048; tk = r >> 5; tn = r & 31;
    } else {
        int r = bid - 448; src = W2; dst = W2t; K = 2048; N = 512; tk = r >> 3; tn = r & 7;
    }
    int k0 = tk * 64, n0 = tn * 64;
    int rr = threadIdx.x >> 6, c = threadIdx.x & 63;
#pragma unroll
    for (int i = 0; i < 16; i++) {
        int row = i * 4 + rr;
        tile[row][c] = f2bf(src[(size_t)(k0 + row) * N + n0 + c]);
    }
    __syncthreads();
#pragma unroll
    for (int i = 0; i < 16; i++) {
        int row = i * 4 + rr;   // n-local
        dst[(size_t)(n0 + row) * K + k0 + c] = tile[c][row];
    }
}

// ---------------- layernorm: one wave per 512-wide row, out bf16 ----------------
__global__ __launch_bounds__(256) void k_layernorm(const float* __restrict__ X,
                                                   const float* __restrict__ g,
                                                   const float* __restrict__ be,
                                                   ushort_t* __restrict__ Out) {
    int row  = blockIdx.x * 4 + (threadIdx.x >> 6);
    int lane = threadIdx.x & 63;
    const float* x = X + (size_t)row * D_MODEL + lane * 8;
    float4 v0 = ((const float4*)x)[0];
    float4 v1 = ((const float4*)x)[1];
    float vals[8] = {v0.x, v0.y, v0.z, v0.w, v1.x, v1.y, v1.z, v1.w};
    float s = 0.f, sq = 0.f;
#pragma unroll
    for (int j = 0; j < 8; j++) { s += vals[j]; sq += vals[j] * vals[j]; }
#pragma unroll
    for (int off = 32; off; off >>= 1) { s += __shfl_xor(s, off); sq += __shfl_xor(sq, off); }
    float mu  = s * (1.0f / D_MODEL);
    float var = sq * (1.0f / D_MODEL) - mu * mu;
    float inv = rsqrtf(var + 1e-5f);
    const float* gp  = g  + lane * 8;
    const float* bp  = be + lane * 8;
    float4 g0 = ((const float4*)gp)[0], g1v = ((const float4*)gp)[1];
    float4 b0 = ((const float4*)bp)[0], b1v = ((const float4*)bp)[1];
    float gs[8] = {g0.x, g0.y, g0.z, g0.w, g1v.x, g1v.y, g1v.z, g1v.w};
    float bs[8] = {b0.x, b0.y, b0.z, b0.w, b1v.x, b1v.y, b1v.z, b1v.w};
    ushort_t o[8];
#pragma unroll
    for (int j = 0; j < 8; j++) o[j] = f2bf((vals[j] - mu) * inv * gs[j] + bs[j]);
    ushort_t* op = Out + (size_t)row * D_MODEL + lane * 8;
    *(uint4*)op = *(uint4*)o;
}

// ======== m97-style GEMM core: 128xBN tile, BK=32, global_load_lds double-buffer =========
static __device__ __forceinline__ void stage_tile(const ushort_t* __restrict__ G, int K,
                                                  ushort_t* L, int nchunks, int koff,
                                                  int w, int l) {
#pragma unroll
    for (int n = w; n < nchunks; n += 4) {
        const ushort_t* g = G + (size_t)(n * 16 + (l >> 2)) * K + koff + (l & 3) * 8;
        __builtin_amdgcn_global_load_lds((const __attribute__((address_space(1))) void*)g,
                                         (__attribute__((address_space(3))) void*)(L + n * 512),
                                         16, 0, 0);
    }
}

template <int JW>
static __device__ __forceinline__ void gemm_core2(const ushort_t* __restrict__ A,
                                                  const ushort_t* __restrict__ Bt,
                                                  int K, int m0, int n0,
                                                  ushort_t* As, ushort_t* Bs,
                                                  float4v acc[4][JW]) {
    const int BBUF = JW * 1024;
    int t = threadIdx.x, w = t >> 6, l = t & 63, q = l >> 4, lm = l & 15;
    int mb = (w & 1) * 64, nb = (w >> 1) * (JW * 16);
    const ushort_t* Ab = A + (size_t)m0 * K;
    const ushort_t* Bb = Bt + (size_t)n0 * K;
    int T = K >> 5;

    stage_tile(Ab, K, As, 8, 0, w, l);
    stage_tile(Bb, K, Bs, 2 * JW, 0, w, l);
    __syncthreads();

    for (int kt = 0; kt < T; kt++) {
        int cur = kt & 1;
        if (kt + 1 < T) {
            stage_tile(Ab, K, As + (1 - cur) * 4096, 8, (kt + 1) * 32, w, l);
            stage_tile(Bb, K, Bs + (1 - cur) * BBUF, 2 * JW, (kt + 1) * 32, w, l);
        }
        const ushort_t* asb = As + cur * 4096;
        const ushort_t* bsb = Bs + cur * BBUF;
        short8 a[4], b[JW];
#pragma unroll
        for (int i = 0; i < 4; i++) a[i] = *(const short8*)&asb[(mb + 16 * i + lm) * 32 + q * 8];
#pragma unroll
        for (int j = 0; j < JW; j++) b[j] = *(const short8*)&bsb[(nb + 16 * j + lm) * 32 + q * 8];
#pragma unroll
        for (int i = 0; i < 4; i++)
#pragma unroll
            for (int j = 0; j < JW; j++)
                acc[i][j] = __builtin_amdgcn_mfma_f32_16x16x32_bf16(a[i], b[j], acc[i][j], 0, 0, 0);
        __syncthreads();
    }
}

// ---------------- fused QKV projection (N=1536): q,k head-layout; v transposed ------------
__global__ __launch_bounds__(256) void k_gemm_qkv(const ushort_t* __restrict__ A,
                                                  const ushort_t* __restrict__ Bt,
                                                  const float* __restrict__ bq,
                                                  const float* __restrict__ bk,
                                                  const float* __restrict__ bv,
                                                  ushort_t* __restrict__ qb,
                                                  ushort_t* __restrict__ kb,
                                                  ushort_t* __restrict__ vt) {
    __shared__ __align__(16) ushort_t As[8192];
    __shared__ __align__(16) ushort_t Bs[8192];
    int m0 = blockIdx.x * 128, n0 = blockIdx.y * 128;
    float4v acc[4][4];
#pragma unroll
    for (int i = 0; i < 4; i++)
#pragma unroll
        for (int j = 0; j < 4; j++) acc[i][j] = (float4v){0.f, 0.f, 0.f, 0.f};
    gemm_core2<4>(A, Bt, D_MODEL, m0, n0, As, Bs, acc);

    int t = threadIdx.x, w = t >> 6, l = t & 63, q = l >> 4, lm = l & 15;
    int mb = (w & 1) * 64, nb = (w >> 1) * 64;
    int mat = n0 >> 9, c0 = n0 & 511;
    const float* bias = (mat == 0) ? bq : ((mat == 1) ? bk : bv);
#pragma unroll
    for (int j = 0; j < 4; j++) {
        int cl = c0 + nb + 16 * j + lm;
        int hh = cl >> 6, dh = cl & 63;
        float bvv = bias[cl];
#pragma unroll
        for (int i = 0; i < 4; i++) {
            int mr0 = m0 + mb + 16 * i + q * 4;
            int bb = mr0 >> 11, ss0 = mr0 & (SEQ - 1);
            if (mat == 2) {
                union { ushort_t s[4]; uint2 v; } pk;
#pragma unroll
                for (int r = 0; r < 4; r++) pk.s[r] = f2bf(acc[i][j][r] + bvv);
                *(uint2*)&vt[((size_t)(bb * N_HEADS + hh) * D_HEAD + dh) * SEQ + ss0] = pk.v;
            } else {
                ushort_t* dst = (mat == 0) ? qb : kb;
                float sc = (mat == 0) ? QSCALE_L2E : 1.0f;
#pragma unroll
                for (int r = 0; r < 4; r++)
                    dst[((size_t)(bb * N_HEADS + hh) * SEQ + ss0 + r) * D_HEAD + dh] =
                        f2bf((acc[i][j][r] + bvv) * sc);
            }
        }
    }
}

// ---------------- FFN1: relu(yn @ W1 + b1) -> bf16 row-major ------------------------------
__global__ __launch_bounds__(256) void k_gemm_ffn1(const ushort_t* __restrict__ A,
                                                   const ushort_t* __restrict__ Bt,
                                                   const float* __restrict__ b1,
                                                   ushort_t* __restrict__ hb) {
    __shared__ __align__(16) ushort_t As[8192];
    __shared__ __align__(16) ushort_t Bs[8192];
    int m0 = blockIdx.x * 128, n0 = blockIdx.y * 128;
    float4v acc[4][4];
#pragma unroll
    for (int i = 0; i < 4; i++)
#pragma unroll
        for (int j = 0; j < 4; j++) acc[i][j] = (float4v){0.f, 0.f, 0.f, 0.f};
    gemm_core2<4>(A, Bt, D_MODEL, m0, n0, As, Bs, acc);

    int t = threadIdx.x, w = t >> 6, l = t & 63, q = l >> 4, lm = l & 15;
    int mb = (w & 1) * 64, nb = (w >> 1) * 64;
#pragma unroll
    for (int j = 0; j < 4; j++) {
        int cl = n0 + nb + 16 * j + lm;
        float bvv = b1[cl];
#pragma unroll
        for (int i = 0; i < 4; i++) {
            int mr0 = m0 + mb + 16 * i + q * 4;
#pragma unroll
            for (int r = 0; r < 4; r++)
                hb[(size_t)(mr0 + r) * D_FF + cl] = f2bf(fmaxf(acc[i][j][r] + bvv, 0.f));
        }
    }
}

// ---------------- FFN2: hb @ W2 + b2 + residual -> f32 out (128x64 tile) ------------------
__global__ __launch_bounds__(256) void k_gemm_ffn2(const ushort_t* __restrict__ A,
                                                   const ushort_t* __restrict__ Bt,
                                                   const float* __restrict__ b2,
                                                   const float* __restrict__ res,
                                                   float* __restrict__ out) {
    __shared__ __align__(16) ushort_t As[8192];
    __shared__ __align__(16) ushort_t Bs[4096];
    int m0 = blockIdx.x * 128, n0 = blockIdx.y * 64;
    float4v acc[4][2];
#pragma unroll
    for (int i = 0; i < 4; i++)
#pragma unroll
        for (int j = 0; j < 2; j++) acc[i][j] = (float4v){0.f, 0.f, 0.f, 0.f};
    gemm_core2<2>(A, Bt, D_FF, m0, n0, As, Bs, acc);

    int t = threadIdx.x, w = t >> 6, l = t & 63, q = l >> 4, lm = l & 15;
    int mb = (w & 1) * 64, nb = (w >> 1) * 32;
#pragma unroll
    for (int j = 0; j < 2; j++) {
        int cl = n0 + nb + 16 * j + lm;
        float bvv = b2[cl];
#pragma unroll
        for (int i = 0; i < 4; i++) {
            int mr0 = m0 + mb + 16 * i + q * 4;
#pragma unroll
            for (int r = 0; r < 4; r++) {
                size_t idx = (size_t)(mr0 + r) * D_MODEL + cl;
                out[idx] = acc[i][j][r] + bvv + res[idx];
            }
        }
    }
}

// ---------------- fused sigmoid attention v7: R7 + register-P PV (no P LDS) ---------------
// 512 thr / 8 waves; block = 128 Q-rows. Wave w: Q-group g=w>>1 (32 rows), t-half th=w&1.
// S^T C-layout registers, sigmoided + packed, are DIRECTLY valid 16x16x16 B-frags (k=4q+r);
// V^T rows from LDS are A-frags (m=d, k=t) -> PV entirely in registers, no P round-trip.
// O^T accumulators give each lane 4 consecutive d -> float4 pair-reduction + epilogue.
__global__ __launch_bounds__(512) void k_attention(const ushort_t* __restrict__ Q,
                                                   const ushort_t* __restrict__ Kb,
                                                   const ushort_t* __restrict__ Vt,
                                                   const float* __restrict__ X,
                                                   float* __restrict__ Y) {
    __shared__ __align__(16) char smem[36864];
    ushort_t* Ks = (ushort_t*)smem;                    // [2][64][72] = 18432 B
    ushort_t* Vs = (ushort_t*)(smem + 18432);          // [2][64][72] = 18432 B (V^T: [d][t])
    float*  Osum = (float*)smem;                       // after loop: 128 x 68 f32 (34.8 KB)

    int bh = blockIdx.y;
    int b = bh >> 3, h = bh & 7;
    size_t base = (size_t)bh * SEQ * D_HEAD;
    int s0 = blockIdx.x * 128;
    int t = threadIdx.x, w = t >> 6, l = t & 63, q = l >> 4, lm = l & 15;
    int g = w >> 1, th = w & 1;
    int srow = t >> 3, sc = (t & 7) * 8;               // staging: 512 thr x 16B = 8 KB tile

    // Q fragments in registers: rows s0 + 32g + 16nt + lm
    short8 qf[2][2];
#pragma unroll
    for (int nt = 0; nt < 2; nt++)
#pragma unroll
        for (int kc = 0; kc < 2; kc++) {
            const ushort_t* qg = Q + base + (size_t)(s0 + 32 * g + 16 * nt + lm) * D_HEAD + kc * 32 + q * 8;
            uint4 u = *(const uint4*)qg;
            qf[nt][kc] = *(const short8*)&u;
        }

    // O^T partials: o[nt][dj], lane holds O[s=s0+32g+16nt+lm][d=16dj+4q+r]
    float4v o[2][4];
#pragma unroll
    for (int nt = 0; nt < 2; nt++)
#pragma unroll
        for (int dj = 0; dj < 4; dj++) o[nt][dj] = (float4v){0.f, 0.f, 0.f, 0.f};

    uint4 kr, vr;
    const ushort_t* kg0 = Kb + base + (size_t)srow * D_HEAD + sc;
    const ushort_t* vg0 = Vt + base + (size_t)srow * SEQ + sc;

    kr = *(const uint4*)(kg0); vr = *(const uint4*)(vg0);
    *(uint4*)&Ks[srow * 72 + sc] = kr; *(uint4*)&Vs[srow * 72 + sc] = vr;
    kr = *(const uint4*)(kg0 + 64 * D_HEAD); vr = *(const uint4*)(vg0 + 64);
    __syncthreads();

    for (int tt = 0; tt < SEQ / 64; tt++) {
        int cur = tt & 1;
        const ushort_t* ksb = Ks + cur * 4608;
        const ushort_t* vsb = Vs + cur * 4608;
        // --- K fragments: this wave's t-half (rows 32*th + 16*mt + lm) ---
        short8 kf[2][2];
#pragma unroll
        for (int mt = 0; mt < 2; mt++)
#pragma unroll
            for (int kc = 0; kc < 2; kc++)
                kf[mt][kc] = *(const short8*)&ksb[(32 * th + 16 * mt + lm) * 72 + kc * 32 + q * 8];
        // --- S^T = K Q~^T : S~[t = tt*64+32th+16mt+4q+r][s = s0+32g+16nt+lm] ---
        float4v st[2][2];
#pragma unroll
        for (int mt = 0; mt < 2; mt++)
#pragma unroll
            for (int nt = 0; nt < 2; nt++) st[mt][nt] = (float4v){0.f, 0.f, 0.f, 0.f};
#pragma unroll
        for (int kc = 0; kc < 2; kc++)
#pragma unroll
            for (int mt = 0; mt < 2; mt++)
#pragma unroll
                for (int nt = 0; nt < 2; nt++)
                    st[mt][nt] = __builtin_amdgcn_mfma_f32_16x16x32_bf16(kf[mt][kc], qf[nt][kc], st[mt][nt], 0, 0, 0);
        // --- sigmoid -> packed register P-fragments (16x16x16 B-layout: n=lm, k=4q+r) ---
        short4v pf[2][2];
#pragma unroll
        for (int mt = 0; mt < 2; mt++)
#pragma unroll
            for (int nt = 0; nt < 2; nt++) {
                union { unsigned int u[2]; short4v v; } pk;
                pk.u[0] = pack2bf(sig2(st[mt][nt][0]), sig2(st[mt][nt][1]));
                pk.u[1] = pack2bf(sig2(st[mt][nt][2]), sig2(st[mt][nt][3]));
                pf[mt][nt] = pk.v;
            }
        // --- O^T += V^T P : A = V^T frag (m=d=16dj+lm, k=t), B = P-frag; K=16 MFMA ---
#pragma unroll
        for (int mt = 0; mt < 2; mt++) {
            short4v vf[4];
#pragma unroll
            for (int dj = 0; dj < 4; dj++)
                vf[dj] = *(const short4v*)&vsb[(16 * dj + lm) * 72 + 32 * th + 16 * mt + 4 * q];
#pragma unroll
            for (int dj = 0; dj < 4; dj++)
#pragma unroll
                for (int nt = 0; nt < 2; nt++)
                    o[nt][dj] = __builtin_amdgcn_mfma_f32_16x16x16bf16_1k(vf[dj], pf[mt][nt], o[nt][dj], 0, 0, 0);
        }
        // --- pipeline: regs -> other buf; prefetch tt+2 ---
        if (tt + 1 < SEQ / 64) {
            int nxt = 1 - cur;
            *(uint4*)&Ks[nxt * 4608 + srow * 72 + sc] = kr;
            *(uint4*)&Vs[nxt * 4608 + srow * 72 + sc] = vr;
            if (tt + 2 < SEQ / 64) {
                kr = *(const uint4*)(kg0 + (size_t)(tt + 2) * 64 * D_HEAD);
                vr = *(const uint4*)(vg0 + (tt + 2) * 64);
            }
        }
        __syncthreads();
    }

    // --- pair-wave O reduction into Osum (float4; stride 68 keeps 16B alignment) ---
    __syncthreads();
    if (th == 0) {
#pragma unroll
        for (int nt = 0; nt < 2; nt++)
#pragma unroll
            for (int dj = 0; dj < 4; dj++) {
                float4v v = o[nt][dj];
                *(float4*)&Osum[(32 * g + 16 * nt + lm) * 68 + 16 * dj + 4 * q] =
                    make_float4(v[0], v[1], v[2], v[3]);
            }
    }
    __syncthreads();
    if (th == 1) {
#pragma unroll
        for (int nt = 0; nt < 2; nt++)
#pragma unroll
            for (int dj = 0; dj < 4; dj++) {
                float* p = &Osum[(32 * g + 16 * nt + lm) * 68 + 16 * dj + 4 * q];
                float4 old = *(float4*)p;
                float4v v = o[nt][dj];
                *(float4*)p = make_float4(old.x + v[0], old.y + v[1], old.z + v[2], old.w + v[3]);
            }
    }
    __syncthreads();

    // --- epilogue: Y = X + O (thread t: row t>>2, 16 cols) ---
    {
        int row = t >> 2, c0 = (t & 3) * 16;
        size_t gro = ((size_t)(b * SEQ + s0 + row)) * D_MODEL + h * D_HEAD + c0;
        const float* xp = X + gro;
        float* yp = Y + gro;
        const float* os = &Osum[row * 68 + c0];
#pragma unroll
        for (int i = 0; i < 4; i++) {
            float4 xv = *(const float4*)(xp + i * 4);
            float4 ov = *(const float4*)(os + i * 4);
            float4 rr;
            rr.x = xv.x + ov.x; rr.y = xv.y + ov.y;
            rr.z = xv.z + ov.z; rr.w = xv.w + ov.w;
            *(float4*)(yp + i * 4) = rr;
        }
    }
}

extern "C" void kernel_launch(void* const* d_in, const int* in_sizes, int n_in,
                              void* d_out, int out_size, void* d_ws, size_t ws_size,
                              hipStream_t stream) {
    const float* x   = (const float*)d_in[0];
    const float* Wq  = (const float*)d_in[1];
    const float* bq  = (const float*)d_in[2];
    const float* Wk  = (const float*)d_in[3];
    const float* bk  = (const float*)d_in[4];
    const float* Wv  = (const float*)d_in[5];
    const float* bv  = (const float*)d_in[6];
    const float* W1  = (const float*)d_in[7];
    const float* b1  = (const float*)d_in[8];
    const float* W2  = (const float*)d_in[9];
    const float* b2  = (const float*)d_in[10];
    const float* g1  = (const float*)d_in[11];
    const float* be1 = (const float*)d_in[12];
    const float* g2  = (const float*)d_in[13];
    const float* be2 = (const float*)d_in[14];
    float* out = (float*)d_out;

    char* p = (char*)d_ws;
    ushort_t* xn    = (ushort_t*)p; p += (size_t)NTOK * D_MODEL * 2;
    ushort_t* yn    = (ushort_t*)p; p += (size_t)NTOK * D_MODEL * 2;
    float*    y     = (float*)p;    p += (size_t)NTOK * D_MODEL * 4;
    ushort_t* qb    = (ushort_t*)p; p += (size_t)NTOK * D_MODEL * 2;
    ushort_t* kb    = (ushort_t*)p; p += (size_t)NTOK * D_MODEL * 2;
    ushort_t* vt    = (ushort_t*)p; p += (size_t)NTOK * D_MODEL * 2;
    ushort_t* hb    = (ushort_t*)p; p += (size_t)NTOK * D_FF * 2;
    ushort_t* Wqkvt = (ushort_t*)p; p += (size_t)3 * D_MODEL * D_MODEL * 2;
    ushort_t* W1t   = (ushort_t*)p; p += (size_t)D_MODEL * D_FF * 2;
    ushort_t* W2t   = (ushort_t*)p; p += (size_t)D_FF * D_MODEL * 2;

    k_prep_weights<<<704, 256, 0, stream>>>(Wq, Wk, Wv, W1, W2, Wqkvt, W1t, W2t);

    k_layernorm<<<NTOK / 4, 256, 0, stream>>>(x, g1, be1, xn);

    dim3 gq(NTOK / 128, (3 * D_MODEL) / 128);
    k_gemm_qkv<<<gq, 256, 0, stream>>>(xn, Wqkvt, bq, bk, bv, qb, kb, vt);

    dim3 ga(SEQ / 128, BATCH * N_HEADS);
    k_attention<<<ga, 512, 0, stream>>>(qb, kb, vt, x, y);

    k_layernorm<<<NTOK / 4, 256, 0, stream>>>(y, g2, be2, yn);

    dim3 g1d(NTOK / 128, D_FF / 128);
    k_gemm_ffn1<<<g1d, 256, 0, stream>>>(yn, W1t, b1, hb);
    dim3 g2d(NTOK / 128, D_MODEL / 64);
    k_gemm_ffn2<<<g2d, 256, 0, stream>>>(hb, W2t, b2, y, out);
}